// Round 1
// baseline (317.002 us; speedup 1.0000x reference)
//
#include <hip/hip_runtime.h>
#include <math.h>

#define MTOT 42000
#define NB 8
#define NCLS 80
#define HIST_BINS 65536
#define CAP_LIST 4096
#define MAXT 256

// ---- workspace byte offsets ----
#define O_OVR 0
#define O_GIX (O_OVR + NB*MTOT*4)
#define O_LSC (O_GIX + NB*MTOT*4)
#define O_BCE (O_LSC + NB*MTOT*4)
#define O_BPI (O_BCE + NB*MTOT*4)
#define O_LST (O_BPI + MAXT*4)
#define O_CNT (O_LST + NB*MAXT*4)
#define O_HIST ((((O_CNT + NB*4) + 255)/256)*256)
#define O_ACC (O_HIST + NB*HIST_BINS*4)
#define O_BIN (O_ACC + 256)
// acc floats at O_ACC: [0]=sum_xy [1]=sum_wh [2]=sum_cls [3]=sum_bce_pos [4]=sum_bce_neg
// acc ints at O_ACC+64: [0]=num_pos [1]=negsel_cnt [2..9]=bstar[i] [10..17]=r[i] [18..25]=listn[i]

__device__ __forceinline__ float iou_cxcywh(float acx,float acy,float aw,float ah,
                                            float bcx,float bcy,float bw,float bh){
  float ax0=acx-aw*0.5f, ay0=acy-ah*0.5f, ax1=acx+aw*0.5f, ay1=acy+ah*0.5f;
  float bx0=bcx-bw*0.5f, by0=bcy-bh*0.5f, bx1=bcx+bw*0.5f, by1=bcy+bh*0.5f;
  float tlx=fmaxf(ax0,bx0), tly=fmaxf(ay0,by0);
  float brx=fminf(ax1,bx1), bry=fminf(ay1,by1);
  float wx=fmaxf(brx-tlx,0.f), wy=fmaxf(bry-tly,0.f);
  float inter=wx*wy;
  return inter/(aw*ah+bw*bh-inter+1e-9f);
}

__device__ __forceinline__ float sl1(float x){
  float ax=fabsf(x); return ax<1.f ? 0.5f*ax*ax : ax-0.5f;
}

// build per-image target lists (preserving t order)
__global__ void k_prep(const float* __restrict__ tg, int nt, int* __restrict__ list, int* __restrict__ cnt){
  if(threadIdx.x==0 && blockIdx.x==0){
    int c[NB];
    for(int i=0;i<NB;i++) c[i]=0;
    for(int t=0;t<nt;t++){
      int img=(int)tg[t*6];
      if(img>=0 && img<NB && c[img]<MAXT){ list[img*MAXT+c[img]]=t; c[img]++; }
    }
    for(int i=0;i<NB;i++) cnt[i]=c[i];
  }
}

// per (image, prior): max / argmax IoU over that image's targets (first-index tie-break)
__global__ void k_match(const float* __restrict__ tg, const float* __restrict__ priors,
                        const int* __restrict__ list, const int* __restrict__ cnt,
                        float* __restrict__ ovr, int* __restrict__ gix){
  __shared__ float st[MAXT*6];
  __shared__ int   sidx[MAXT];
  int i = blockIdx.y;
  int n = cnt[i];
  for(int j=threadIdx.x;j<n;j+=blockDim.x){
    int t=list[i*MAXT+j];
    sidx[j]=t;
    #pragma unroll
    for(int q=0;q<6;q++) st[j*6+q]=tg[t*6+q];
  }
  __syncthreads();
  int m = blockIdx.x*blockDim.x + threadIdx.x;
  if(m>=MTOT) return;
  float4 pr = ((const float4*)priors)[m];
  float maxv=-1.0f; int bi=0;           // matches argmax over iv (invalid rows = -1)
  for(int j=0;j<n;j++){
    float v=iou_cxcywh(st[j*6+2],st[j*6+3],st[j*6+4],st[j*6+5], pr.x,pr.y,pr.z,pr.w);
    if(v>maxv){ maxv=v; bi=sidx[j]; }
  }
  ovr[i*MTOT+m]=maxv; gix[i*MTOT+m]=bi;
}

// per target: argmax IoU over all priors (first-index tie-break)
__global__ void k_bestprior(const float* __restrict__ tg, const float* __restrict__ priors,
                            int nt, int* __restrict__ bpi){
  int t=blockIdx.x; if(t>=nt) return;
  float acx=tg[t*6+2],acy=tg[t*6+3],aw=tg[t*6+4],ah=tg[t*6+5];
  float bv=-2.f; int bm=0;
  for(int m=threadIdx.x;m<MTOT;m+=blockDim.x){
    float4 pr=((const float4*)priors)[m];
    float v=iou_cxcywh(acx,acy,aw,ah,pr.x,pr.y,pr.z,pr.w);
    if(v>bv){ bv=v; bm=m; }
  }
  __shared__ float sv[256]; __shared__ int sm[256];
  sv[threadIdx.x]=bv; sm[threadIdx.x]=bm;
  __syncthreads();
  for(int s=128;s>0;s>>=1){
    if(threadIdx.x<s){
      if(sv[threadIdx.x+s]>sv[threadIdx.x] ||
         (sv[threadIdx.x+s]==sv[threadIdx.x] && sm[threadIdx.x+s]<sm[threadIdx.x])){
        sv[threadIdx.x]=sv[threadIdx.x+s]; sm[threadIdx.x]=sm[threadIdx.x+s];
      }
    }
    __syncthreads();
  }
  if(threadIdx.x==0) bpi[t]=sm[0];
}

// forced-prior scatter: overlap[i][bp[t]] = local_j (t ascending => last-wins)
__global__ void k_scatter(const int* __restrict__ list, const int* __restrict__ cnt,
                          const int* __restrict__ bpi, float* __restrict__ ovr){
  if(threadIdx.x||blockIdx.x) return;
  for(int i=0;i<NB;i++){
    int n=cnt[i];
    for(int j=0;j<n;j++){
      int t=list[i*MAXT+j];
      ovr[i*MTOT + bpi[t]] = (float)j;
    }
  }
}

// main pass: per (i,m) compute loss_c, bce, histogram; positives also contribute box/cls losses
__global__ void k_main(const float* __restrict__ f0,const float* __restrict__ f1,const float* __restrict__ f2,
                       const float* __restrict__ tg,const float* __restrict__ priors,
                       const float* __restrict__ ovr,const int* __restrict__ gix,
                       float* __restrict__ lsc,float* __restrict__ bcearr,
                       unsigned* __restrict__ hist,
                       float* __restrict__ accf,int* __restrict__ acci){
  int gid=blockIdx.x*blockDim.x+threadIdx.x;
  if(gid>=NB*MTOT) return;
  int i=gid/MTOT, m=gid-i*MTOT;
  const float* fp; int hw, loc;
  if(m<32000){ fp=f0; hw=6400; loc=m; }
  else if(m<40000){ fp=f1; hw=1600; loc=m-32000; }
  else { fp=f2; hw=400; loc=m-40000; }
  int a=loc/hw, p=loc-a*hw;
  const float* base = fp + (size_t)(i*425 + a*85)*(size_t)hw + p;

  float ov=ovr[gid]; int gi=gix[gid];
  float tc = tg[gi*6+1] + 1.0f;
  float cls = (ov < 0.5f) ? 0.f : tc;
  bool pos = cls > 0.f;

  float obj = base[(size_t)4*hw];
  float sp = log1pf(expf(-fabsf(obj)));           // log1p(exp(-|obj|))
  float bce = fmaxf(obj,0.f) - (pos?obj:0.f) + sp; // BCE-with-logits, z=posf
  float lc  = pos ? 0.f : (fmaxf(-obj,0.f)+sp);    // -log_sigmoid(obj), zeroed at pos
  lsc[gid]=lc; bcearr[gid]=bce;
  atomicAdd(&hist[(size_t)i*HIST_BINS + (__float_as_uint(lc)>>16)], 1u);

  if(pos){
    float4 pr=((const float4*)priors)[m];
    float bx=tg[gi*6+2],by=tg[gi*6+3],bw=tg[gi*6+4],bh=tg[gi*6+5];
    float tx=(bx-pr.x)/pr.z, ty=(by-pr.y)/pr.w;
    float tw=logf(bw/pr.z), th=logf(bh/pr.w);
    float p0=base[0], p1=base[hw], p2=base[(size_t)2*hw], p3=base[(size_t)3*hw];
    float lxy=sl1(p0-tx)+sl1(p1-ty);
    float lwh=sl1(p2-tw)+sl1(p3-th);
    int label=(int)tc - 1; label=max(0,min(NCLS-1,label));
    float mx=-3.4e38f;
    for(int c=0;c<NCLS;c++){ float v=base[(size_t)(5+c)*hw]; mx=fmaxf(mx,v); }
    float se=0.f, xl=0.f;
    for(int c=0;c<NCLS;c++){
      float v=base[(size_t)(5+c)*hw];
      se += expf(v-mx);
      if(c==label) xl=v;
    }
    float ce = logf(se)+mx-xl;
    atomicAdd(&accf[0],lxy);
    atomicAdd(&accf[1],lwh);
    atomicAdd(&accf[2],ce);
    atomicAdd(&accf[3],bce);
    atomicAdd(&acci[0],1);
  }
}

// per image: find threshold bin for top-k of loss_c (k = min(num_pos, M-num_pos))
__global__ void k_scan(const unsigned* __restrict__ hist, int* __restrict__ acci){
  int i=blockIdx.x;
  int np=acci[0];
  int k=min(np, MTOT-np);
  __shared__ int csum[256];
  __shared__ int suf[256];
  const unsigned* h=hist+(size_t)i*HIST_BINS;
  int c=threadIdx.x;
  int s=0;
  for(int b=0;b<256;b++) s+=(int)h[c*256+b];
  csum[c]=s; __syncthreads();
  if(c==0){
    int run=0;
    for(int cc=255;cc>=0;cc--){ suf[cc]=run; run+=csum[cc]; }
  }
  __syncthreads();
  if(k<=0){ if(c==0){ acci[2+i]=0x7fffffff; acci[10+i]=0; } return; }
  int run=suf[c];                 // count of elements in bins above this chunk
  for(int b=255;b>=0;b--){
    int cb=(int)h[c*256+b];
    if(run<k && run+cb>=k){ acci[2+i]=c*256+b; acci[10+i]=k-run; }
    run+=cb;
  }
}

// select negatives strictly above threshold bin; collect boundary-bin members
__global__ void k_select(const float* __restrict__ lsc,const float* __restrict__ bcearr,
                         int* __restrict__ acci,float* __restrict__ accf,
                         int* __restrict__ binlist){
  int gid=blockIdx.x*blockDim.x+threadIdx.x;
  if(gid>=NB*MTOT) return;
  int i=gid/MTOT;
  int bs=acci[2+i];
  unsigned u=__float_as_uint(lsc[gid]);
  int bin=(int)(u>>16);
  if(bin>bs){
    atomicAdd(&accf[4], bcearr[gid]);
    atomicAdd(&acci[1], 1);
  } else if(bin==bs){
    int idx=atomicAdd(&acci[18+i],1);
    if(idx<CAP_LIST){
      binlist[((size_t)i*CAP_LIST+idx)*2  ]=(int)u;
      binlist[((size_t)i*CAP_LIST+idx)*2+1]=gid;
    }
  }
}

// stable tie-resolution inside the boundary bin (value desc, index asc)
__global__ void k_ties(const float* __restrict__ bcearr,int* __restrict__ acci,
                       float* __restrict__ accf,const int* __restrict__ binlist){
  int i=blockIdx.x;
  if(acci[2+i]==0x7fffffff) return;
  int n=min(acci[18+i],CAP_LIST);
  int r=acci[10+i];
  for(int e=threadIdx.x;e<n;e+=blockDim.x){
    unsigned ue=(unsigned)binlist[((size_t)i*CAP_LIST+e)*2];
    int ge=binlist[((size_t)i*CAP_LIST+e)*2+1];
    int rank=0;
    for(int q=0;q<n;q++){
      unsigned uq=(unsigned)binlist[((size_t)i*CAP_LIST+q)*2];
      int gq=binlist[((size_t)i*CAP_LIST+q)*2+1];
      rank += ((uq>ue) || (uq==ue && gq<ge)) ? 1 : 0;
    }
    if(rank<r){
      atomicAdd(&accf[4], bcearr[ge]);
      atomicAdd(&acci[1], 1);
    }
  }
}

__global__ void k_final(const float* __restrict__ accf,const int* __restrict__ acci,
                        float* __restrict__ out){
  if(threadIdx.x||blockIdx.x) return;
  int np=acci[0];
  float npf=(float)np;
  float den2=fmaxf(2.f*npf,1.f);
  float lbox=accf[0]/den2 + accf[1]/den2;
  float lcls=accf[2]/fmaxf(npf,1.f);
  float selc=(float)(np+acci[1]);
  float lobj=(accf[3]+accf[4])/fmaxf(selc,1.f);
  out[0]=lbox+lcls+lobj;
  out[1]=lbox;
  out[2]=lobj;
  out[3]=lcls;
}

extern "C" void kernel_launch(void* const* d_in, const int* in_sizes, int n_in,
                              void* d_out, int out_size, void* d_ws, size_t ws_size,
                              hipStream_t stream) {
  const float* f0=(const float*)d_in[0];
  const float* f1=(const float*)d_in[1];
  const float* f2=(const float*)d_in[2];
  const float* tg=(const float*)d_in[3];
  const float* priors=(const float*)d_in[4];
  int nt = in_sizes[3]/6;

  char* ws=(char*)d_ws;
  float*    ovr    =(float*)   (ws+O_OVR);
  int*      gix    =(int*)     (ws+O_GIX);
  float*    lsc    =(float*)   (ws+O_LSC);
  float*    bcearr =(float*)   (ws+O_BCE);
  int*      bpi    =(int*)     (ws+O_BPI);
  int*      list   =(int*)     (ws+O_LST);
  int*      cnt    =(int*)     (ws+O_CNT);
  unsigned* hist   =(unsigned*)(ws+O_HIST);
  float*    accf   =(float*)   (ws+O_ACC);
  int*      acci   =(int*)     (ws+O_ACC+64);
  int*      binlist=(int*)     (ws+O_BIN);

  // zero hist + accumulators + list counters (every call: graph replays must be deterministic)
  hipMemsetAsync(ws+O_HIST, 0, (size_t)(O_BIN-O_HIST), stream);

  k_prep<<<1,64,0,stream>>>(tg,nt,list,cnt);
  dim3 gm((MTOT+255)/256, NB);
  k_match<<<gm,256,0,stream>>>(tg,priors,list,cnt,ovr,gix);
  k_bestprior<<<nt,256,0,stream>>>(tg,priors,nt,bpi);
  k_scatter<<<1,1,0,stream>>>(list,cnt,bpi,ovr);
  int tot=NB*MTOT, blocks=(tot+255)/256;
  k_main<<<blocks,256,0,stream>>>(f0,f1,f2,tg,priors,ovr,gix,lsc,bcearr,hist,accf,acci);
  k_scan<<<NB,256,0,stream>>>(hist,acci);
  k_select<<<blocks,256,0,stream>>>(lsc,bcearr,acci,accf,binlist);
  k_ties<<<NB,256,0,stream>>>(bcearr,acci,accf,binlist);
  k_final<<<1,1,0,stream>>>(accf,acci,(float*)d_out);
}